// Round 1
// baseline (5368.095 us; speedup 1.0000x reference)
//
#include <hip/hip_runtime.h>
#include <math.h>

#define NND 100000
#define NE  1000000
#define HD  128

// ---------------- degree / dinv ----------------
__global__ __launch_bounds__(256) void deg_init_k(float* deg) {
    int i = blockIdx.x * 256 + threadIdx.x;
    if (i < NND) deg[i] = 1.0f;
}

__global__ __launch_bounds__(256) void deg_count_k(const int* __restrict__ dst,
                                                   float* __restrict__ deg) {
    int e = blockIdx.x * 256 + threadIdx.x;
    if (e < NE) atomicAdd(&deg[dst[e]], 1.0f);
}

__global__ __launch_bounds__(256) void deg_rsqrt_k(float* deg) {
    int i = blockIdx.x * 256 + threadIdx.x;
    if (i < NND) deg[i] = rsqrtf(deg[i]);
}

// ---------------- GEMM: H = X @ W  (X: [NND,128], W: [128,128]) ----------------
// 128x128 output tile per 256-thread block, 8x8 register tile per thread.
__global__ __launch_bounds__(256) void gemm128_k(const float* __restrict__ X,
                                                 const float* __restrict__ W,
                                                 float* __restrict__ Hout) {
    __shared__ float xs[16][128];   // [k][row] (transposed x chunk)
    __shared__ float ws[16][128];   // [k][col]
    const int tid = threadIdx.x;
    const int tx = tid & 15, ty = tid >> 4;
    const int rowBase = blockIdx.x * 128;

    float acc[8][8];
#pragma unroll
    for (int i = 0; i < 8; ++i)
#pragma unroll
        for (int j = 0; j < 8; ++j) acc[i][j] = 0.f;

    for (int k0 = 0; k0 < HD; k0 += 16) {
        // load x chunk (128 rows x 16 k), transpose into xs[k][row]
#pragma unroll
        for (int p = 0; p < 2; ++p) {
            int r  = (tid >> 2) + p * 64;
            int kk = (tid & 3) << 2;
            int grow = rowBase + r;
            float4 v = make_float4(0.f, 0.f, 0.f, 0.f);
            if (grow < NND) v = *(const float4*)(X + (size_t)grow * HD + k0 + kk);
            xs[kk + 0][r] = v.x;
            xs[kk + 1][r] = v.y;
            xs[kk + 2][r] = v.z;
            xs[kk + 3][r] = v.w;
        }
        // load W chunk (16 k x 128 cols)
#pragma unroll
        for (int p = 0; p < 2; ++p) {
            int f  = tid + p * 256;
            int kk = f >> 5, cg = (f & 31) << 2;
            *(float4*)&ws[kk][cg] = *(const float4*)(W + (size_t)(k0 + kk) * HD + cg);
        }
        __syncthreads();
#pragma unroll
        for (int k = 0; k < 16; ++k) {
            float a[8], b[8];
            *(float4*)&a[0] = *(const float4*)&xs[k][ty * 8];
            *(float4*)&a[4] = *(const float4*)&xs[k][ty * 8 + 4];
            *(float4*)&b[0] = *(const float4*)&ws[k][tx * 8];
            *(float4*)&b[4] = *(const float4*)&ws[k][tx * 8 + 4];
#pragma unroll
            for (int i = 0; i < 8; ++i)
#pragma unroll
                for (int j = 0; j < 8; ++j)
                    acc[i][j] = fmaf(a[i], b[j], acc[i][j]);
        }
        __syncthreads();
    }
#pragma unroll
    for (int i = 0; i < 8; ++i) {
        int grow = rowBase + ty * 8 + i;
        if (grow < NND) {
            float4 o0 = make_float4(acc[i][0], acc[i][1], acc[i][2], acc[i][3]);
            float4 o1 = make_float4(acc[i][4], acc[i][5], acc[i][6], acc[i][7]);
            *(float4*)(Hout + (size_t)grow * HD + tx * 8)     = o0;
            *(float4*)(Hout + (size_t)grow * HD + tx * 8 + 4) = o1;
        }
    }
}

// ---------------- edge scatter: agg[dst] += h[src] * norm ----------------
// 32 lanes per edge, each lane handles 4 features (float4 gather + 4 atomics).
__global__ __launch_bounds__(256) void scatter_k(const float* __restrict__ Hm,
                                                 const int* __restrict__ src,
                                                 const int* __restrict__ dst,
                                                 const float* __restrict__ dinv,
                                                 float* __restrict__ agg) {
    const int e = blockIdx.x * 8 + (threadIdx.x >> 5);
    if (e >= NE) return;
    const int lane = threadIdx.x & 31;
    const int s = src[e], d = dst[e];
    const float nrm = dinv[s] * dinv[d];
    float4 v = *(const float4*)(Hm + (size_t)s * HD + lane * 4);
    float* out = agg + (size_t)d * HD + lane * 4;
    atomicAdd(out + 0, v.x * nrm);
    atomicAdd(out + 1, v.y * nrm);
    atomicAdd(out + 2, v.z * nrm);
    atomicAdd(out + 3, v.w * nrm);
}

// ---------------- combine: A = elu(agg + h*dinv^2 + b), in place on agg ----------------
__global__ __launch_bounds__(256) void combine_k(float* __restrict__ agg,
                                                 const float* __restrict__ Hm,
                                                 const float* __restrict__ dinv,
                                                 const float* __restrict__ b) {
    int i = blockIdx.x * 256 + threadIdx.x;   // over NND*32 float4 groups
    if (i >= NND * 32) return;
    int row = i >> 5, c = i & 31;
    float di = dinv[row];
    float d2 = di * di;
    float4 a  = ((const float4*)agg)[i];
    float4 h4 = ((const float4*)Hm)[i];
    float4 b4 = ((const float4*)b)[c];
    float r0 = fmaf(h4.x, d2, a.x) + b4.x;
    float r1 = fmaf(h4.y, d2, a.y) + b4.y;
    float r2 = fmaf(h4.z, d2, a.z) + b4.z;
    float r3 = fmaf(h4.w, d2, a.w) + b4.w;
    r0 = r0 > 0.f ? r0 : expm1f(r0);
    r1 = r1 > 0.f ? r1 : expm1f(r1);
    r2 = r2 > 0.f ? r2 : expm1f(r2);
    r3 = r3 > 0.f ? r3 : expm1f(r3);
    ((float4*)agg)[i] = make_float4(r0, r1, r2, r3);
}

// ---------------- output head: out = A @ Wo + bo ----------------
__global__ __launch_bounds__(256) void out_k(const float* __restrict__ A,
                                             const float* __restrict__ Wo,
                                             const float* __restrict__ bo,
                                             float* __restrict__ out) {
    int row  = blockIdx.x * 4 + (threadIdx.x >> 6);
    int lane = threadIdx.x & 63;
    if (row >= NND) return;
    float2 v = *(const float2*)(A + (size_t)row * HD + lane * 2);
    float2 w = *(const float2*)(Wo + lane * 2);
    float s = v.x * w.x + v.y * w.y;
#pragma unroll
    for (int off = 32; off > 0; off >>= 1) s += __shfl_down(s, off);
    if (lane == 0) out[row] = s + bo[0];
}

extern "C" void kernel_launch(void* const* d_in, const int* in_sizes, int n_in,
                              void* d_out, int out_size, void* d_ws, size_t ws_size,
                              hipStream_t stream) {
    const float* x   = (const float*)d_in[0];
    const int*   ei  = (const int*)d_in[1];
    const int*   src = ei;           // edge_index[0]
    const int*   dst = ei + NE;      // edge_index[1]
    const float* W0 = (const float*)d_in[2];
    const float* b0 = (const float*)d_in[3];
    const float* W1 = (const float*)d_in[4];
    const float* b1 = (const float*)d_in[5];
    const float* W2 = (const float*)d_in[6];
    const float* b2 = (const float*)d_in[7];
    const float* Wo = (const float*)d_in[8];
    const float* bo = (const float*)d_in[9];
    float* out = (float*)d_out;

    // workspace layout
    float* dinv = (float*)d_ws;                 // NND floats (padded to 102400)
    float* Hb   = dinv + 102400;                // NND*128
    float* Ab   = Hb + (size_t)NND * HD;        // NND*128

    // degree -> dinv (constant across layers)
    deg_init_k<<<(NND + 255) / 256, 256, 0, stream>>>(dinv);
    deg_count_k<<<(NE + 255) / 256, 256, 0, stream>>>(dst, dinv);
    deg_rsqrt_k<<<(NND + 255) / 256, 256, 0, stream>>>(dinv);

    const float* Ws[3] = {W0, W1, W2};
    const float* bs[3] = {b0, b1, b2};
    const float* cur = x;
    for (int l = 0; l < 3; ++l) {
        gemm128_k<<<(NND + 127) / 128, 256, 0, stream>>>(cur, Ws[l], Hb);
        hipMemsetAsync(Ab, 0, (size_t)NND * HD * sizeof(float), stream);
        scatter_k<<<NE / 8, 256, 0, stream>>>(Hb, src, dst, dinv, Ab);
        combine_k<<<(NND * 32 + 255) / 256, 256, 0, stream>>>(Ab, Hb, dinv, bs[l]);
        cur = Ab;
    }
    out_k<<<(NND + 3) / 4, 256, 0, stream>>>(Ab, Wo, bo, out);
}

// Round 2
// 717.711 us; speedup vs baseline: 7.4795x; 7.4795x over previous
//
#include <hip/hip_runtime.h>
#include <math.h>

#define NND 100000
#define NE  1000000
#define HD  128

// ---------------- CSR build ----------------
__global__ __launch_bounds__(256) void hist_k(const int* __restrict__ dst,
                                              int* __restrict__ cnt) {
    int e = blockIdx.x * 256 + threadIdx.x;
    if (e < NE) atomicAdd(&cnt[dst[e]], 1);
}

__global__ __launch_bounds__(256) void dinv_k(const int* __restrict__ cnt,
                                              float* __restrict__ dinv) {
    int i = blockIdx.x * 256 + threadIdx.x;
    if (i < NND) dinv[i] = rsqrtf((float)cnt[i] + 1.0f);
}

// single-block exclusive scan of cnt[NND] -> rowptr[NND+1]
__global__ __launch_bounds__(1024) void scan_k(const int* __restrict__ cnt,
                                               int* __restrict__ rowptr) {
    __shared__ int part[1024];
    const int t = threadIdx.x;
    const int chunk = (NND + 1023) / 1024;   // 98
    const int base = t * chunk;
    int s = 0;
    for (int i = 0; i < chunk; ++i) {
        int idx = base + i;
        if (idx < NND) s += cnt[idx];
    }
    part[t] = s;
    __syncthreads();
    for (int off = 1; off < 1024; off <<= 1) {
        int u = (t >= off) ? part[t - off] : 0;
        __syncthreads();
        part[t] += u;
        __syncthreads();
    }
    int run = part[t] - s;   // exclusive prefix
    for (int i = 0; i < chunk; ++i) {
        int idx = base + i;
        if (idx < NND) { rowptr[idx] = run; run += cnt[idx]; }
    }
    if (t == 1023) rowptr[NND] = run;   // last thread's range is past NND, run == total
}

__global__ __launch_bounds__(256) void fill_k(const int* __restrict__ src,
                                              const int* __restrict__ dst,
                                              const int* __restrict__ rowptr,
                                              int* __restrict__ cur,
                                              int* __restrict__ col) {
    int e = blockIdx.x * 256 + threadIdx.x;
    if (e >= NE) return;
    int d = dst[e];
    int pos = rowptr[d] + atomicAdd(&cur[d], 1);
    col[pos] = src[e];
}

// ---------------- GEMM: Hs = (X @ W) * dinv[row] ----------------
__global__ __launch_bounds__(256) void gemm128s_k(const float* __restrict__ X,
                                                  const float* __restrict__ W,
                                                  const float* __restrict__ dinv,
                                                  float* __restrict__ Hout) {
    __shared__ float xs[16][128];   // [k][row]
    __shared__ float ws[16][128];   // [k][col]
    const int tid = threadIdx.x;
    const int tx = tid & 15, ty = tid >> 4;
    const int rowBase = blockIdx.x * 128;

    float acc[8][8];
#pragma unroll
    for (int i = 0; i < 8; ++i)
#pragma unroll
        for (int j = 0; j < 8; ++j) acc[i][j] = 0.f;

    for (int k0 = 0; k0 < HD; k0 += 16) {
#pragma unroll
        for (int p = 0; p < 2; ++p) {
            int r  = (tid >> 2) + p * 64;
            int kk = (tid & 3) << 2;
            int grow = rowBase + r;
            float4 v = make_float4(0.f, 0.f, 0.f, 0.f);
            if (grow < NND) v = *(const float4*)(X + (size_t)grow * HD + k0 + kk);
            xs[kk + 0][r] = v.x;
            xs[kk + 1][r] = v.y;
            xs[kk + 2][r] = v.z;
            xs[kk + 3][r] = v.w;
        }
#pragma unroll
        for (int p = 0; p < 2; ++p) {
            int f  = tid + p * 256;
            int kk = f >> 5, cg = (f & 31) << 2;
            *(float4*)&ws[kk][cg] = *(const float4*)(W + (size_t)(k0 + kk) * HD + cg);
        }
        __syncthreads();
#pragma unroll
        for (int k = 0; k < 16; ++k) {
            float a[8], b[8];
            *(float4*)&a[0] = *(const float4*)&xs[k][ty * 8];
            *(float4*)&a[4] = *(const float4*)&xs[k][ty * 8 + 4];
            *(float4*)&b[0] = *(const float4*)&ws[k][tx * 8];
            *(float4*)&b[4] = *(const float4*)&ws[k][tx * 8 + 4];
#pragma unroll
            for (int i = 0; i < 8; ++i)
#pragma unroll
                for (int j = 0; j < 8; ++j)
                    acc[i][j] = fmaf(a[i], b[j], acc[i][j]);
        }
        __syncthreads();
    }
#pragma unroll
    for (int i = 0; i < 8; ++i) {
        int grow = rowBase + ty * 8 + i;
        if (grow < NND) {
            float di = dinv[grow];
            float4 o0 = make_float4(acc[i][0] * di, acc[i][1] * di, acc[i][2] * di, acc[i][3] * di);
            float4 o1 = make_float4(acc[i][4] * di, acc[i][5] * di, acc[i][6] * di, acc[i][7] * di);
            *(float4*)(Hout + (size_t)grow * HD + tx * 8)     = o0;
            *(float4*)(Hout + (size_t)grow * HD + tx * 8 + 4) = o1;
        }
    }
}

// ---------------- CSR aggregate + self + bias + ELU ----------------
// 32 lanes per node, float4 per lane. Out = elu(dinv*(Hs_i + sum Hs_j) + b)
__global__ __launch_bounds__(256) void agg_k(const float* __restrict__ Hs,
                                             const int* __restrict__ rowptr,
                                             const int* __restrict__ col,
                                             const float* __restrict__ dinv,
                                             const float* __restrict__ b,
                                             float* __restrict__ Out) {
    const int node = blockIdx.x * 8 + (threadIdx.x >> 5);
    if (node >= NND) return;
    const int lane = threadIdx.x & 31;

    float4 acc = *((const float4*)(Hs + (size_t)node * HD) + lane);   // self term
    const int e0 = rowptr[node], e1 = rowptr[node + 1];
    int e = e0;
    for (; e + 1 < e1; e += 2) {
        int s0 = col[e], s1 = col[e + 1];
        float4 v0 = *((const float4*)(Hs + (size_t)s0 * HD) + lane);
        float4 v1 = *((const float4*)(Hs + (size_t)s1 * HD) + lane);
        acc.x += v0.x + v1.x;
        acc.y += v0.y + v1.y;
        acc.z += v0.z + v1.z;
        acc.w += v0.w + v1.w;
    }
    if (e < e1) {
        int s0 = col[e];
        float4 v0 = *((const float4*)(Hs + (size_t)s0 * HD) + lane);
        acc.x += v0.x; acc.y += v0.y; acc.z += v0.z; acc.w += v0.w;
    }
    const float di = dinv[node];
    float4 b4 = ((const float4*)b)[lane];
    float r0 = fmaf(acc.x, di, b4.x);
    float r1 = fmaf(acc.y, di, b4.y);
    float r2 = fmaf(acc.z, di, b4.z);
    float r3 = fmaf(acc.w, di, b4.w);
    r0 = r0 > 0.f ? r0 : expm1f(r0);
    r1 = r1 > 0.f ? r1 : expm1f(r1);
    r2 = r2 > 0.f ? r2 : expm1f(r2);
    r3 = r3 > 0.f ? r3 : expm1f(r3);
    *((float4*)(Out + (size_t)node * HD) + lane) = make_float4(r0, r1, r2, r3);
}

// ---------------- output head: out = A @ Wo + bo ----------------
__global__ __launch_bounds__(256) void out_k(const float* __restrict__ A,
                                             const float* __restrict__ Wo,
                                             const float* __restrict__ bo,
                                             float* __restrict__ out) {
    int row  = blockIdx.x * 4 + (threadIdx.x >> 6);
    int lane = threadIdx.x & 63;
    if (row >= NND) return;
    float2 v = *(const float2*)(A + (size_t)row * HD + lane * 2);
    float2 w = *(const float2*)(Wo + lane * 2);
    float s = v.x * w.x + v.y * w.y;
#pragma unroll
    for (int off = 32; off > 0; off >>= 1) s += __shfl_down(s, off);
    if (lane == 0) out[row] = s + bo[0];
}

extern "C" void kernel_launch(void* const* d_in, const int* in_sizes, int n_in,
                              void* d_out, int out_size, void* d_ws, size_t ws_size,
                              hipStream_t stream) {
    const float* x   = (const float*)d_in[0];
    const int*   ei  = (const int*)d_in[1];
    const int*   src = ei;           // edge_index[0]
    const int*   dst = ei + NE;      // edge_index[1]
    const float* W0 = (const float*)d_in[2];
    const float* b0 = (const float*)d_in[3];
    const float* W1 = (const float*)d_in[4];
    const float* b1 = (const float*)d_in[5];
    const float* W2 = (const float*)d_in[6];
    const float* b2 = (const float*)d_in[7];
    const float* Wo = (const float*)d_in[8];
    const float* bo = (const float*)d_in[9];
    float* out = (float*)d_out;

    // workspace layout (all 256B-aligned chunks)
    float* dinv   = (float*)d_ws;                       // 102400 floats
    int*   cnt    = (int*)(dinv + 102400);              // 102400 ints
    int*   rowptr = cnt + 102400;                       // 102400 ints (NND+1 used)
    int*   col    = rowptr + 102400;                    // 1000448 ints
    float* Hs     = (float*)(col + 1000448);            // NND*HD floats
    float* Ab     = Hs + (size_t)NND * HD;              // NND*HD floats

    // CSR build (per call; deterministic work)
    hipMemsetAsync(cnt, 0, NND * sizeof(int), stream);
    hist_k<<<(NE + 255) / 256, 256, 0, stream>>>(dst, cnt);
    dinv_k<<<(NND + 255) / 256, 256, 0, stream>>>(cnt, dinv);
    scan_k<<<1, 1024, 0, stream>>>(cnt, rowptr);
    hipMemsetAsync(cnt, 0, NND * sizeof(int), stream);
    fill_k<<<(NE + 255) / 256, 256, 0, stream>>>(src, dst, rowptr, cnt, col);

    const float* Ws[3] = {W0, W1, W2};
    const float* bs[3] = {b0, b1, b2};
    const float* cur = x;
    for (int l = 0; l < 3; ++l) {
        gemm128s_k<<<(NND + 127) / 128, 256, 0, stream>>>(cur, Ws[l], dinv, Hs);
        agg_k<<<(NND + 7) / 8, 256, 0, stream>>>(Hs, rowptr, col, dinv, bs[l], Ab);
        cur = Ab;
    }
    out_k<<<(NND + 3) / 4, 256, 0, stream>>>(Ab, Wo, bo, out);
}

// Round 3
// 523.070 us; speedup vs baseline: 10.2627x; 1.3721x over previous
//
#include <hip/hip_runtime.h>
#include <math.h>

#define NND 100000
#define NE  1000000
#define HD  128
#define NSB 98   // scan blocks: ceil(NND/1024)

// ---------------- CSR build ----------------
__global__ __launch_bounds__(256) void hist_k(const int* __restrict__ dst,
                                              int* __restrict__ cnt) {
    int e = blockIdx.x * 256 + threadIdx.x;
    if (e < NE) atomicAdd(&cnt[dst[e]], 1);
}

__global__ __launch_bounds__(256) void dinv_k(const int* __restrict__ cnt,
                                              float* __restrict__ dinv) {
    int i = blockIdx.x * 256 + threadIdx.x;
    if (i < NND) dinv[i] = rsqrtf((float)cnt[i] + 1.0f);
}

// hierarchical exclusive scan: cnt[NND] -> rowptr[NND+1]
__global__ __launch_bounds__(256) void scan1_k(const int* __restrict__ cnt,
                                               int* __restrict__ rowptr,
                                               int* __restrict__ bsum) {
    __shared__ int ts[256];
    const int t = threadIdx.x, b = blockIdx.x;
    const int base = b * 1024 + t * 4;
    int4 v = make_int4(0, 0, 0, 0);
    if (base + 3 < NND) {
        v = *(const int4*)(cnt + base);
    } else if (base < NND) {
        v.x = cnt[base];
        if (base + 1 < NND) v.y = cnt[base + 1];
        if (base + 2 < NND) v.z = cnt[base + 2];
    }
    int s = v.x + v.y + v.z + v.w;
    ts[t] = s;
    __syncthreads();
    for (int off = 1; off < 256; off <<= 1) {
        int u = (t >= off) ? ts[t - off] : 0;
        __syncthreads();
        ts[t] += u;
        __syncthreads();
    }
    int ex = ts[t] - s;   // exclusive prefix of this thread's 4-chunk
    if (base < NND)     rowptr[base]     = ex;
    if (base + 1 < NND) rowptr[base + 1] = ex + v.x;
    if (base + 2 < NND) rowptr[base + 2] = ex + v.x + v.y;
    if (base + 3 < NND) rowptr[base + 3] = ex + v.x + v.y + v.z;
    if (t == 255) bsum[b] = ts[255];
}

__global__ __launch_bounds__(128) void scan2_k(int* __restrict__ bsum) {
    __shared__ int ts[128];
    const int t = threadIdx.x;
    int v = (t < NSB) ? bsum[t] : 0;
    ts[t] = v;
    __syncthreads();
    for (int off = 1; off < 128; off <<= 1) {
        int u = (t >= off) ? ts[t - off] : 0;
        __syncthreads();
        ts[t] += u;
        __syncthreads();
    }
    if (t < NSB) bsum[t] = ts[t] - v;   // exclusive
}

__global__ __launch_bounds__(256) void scan3_k(int* __restrict__ rowptr,
                                               const int* __restrict__ bsum) {
    const int b = blockIdx.x, t = threadIdx.x;
    const int off = bsum[b];
    const int base = b * 1024 + t * 4;
#pragma unroll
    for (int i = 0; i < 4; ++i) {
        int idx = base + i;
        if (idx < NND) rowptr[idx] += off;
    }
    if (b == 0 && t == 0) rowptr[NND] = NE;
}

__global__ __launch_bounds__(256) void fill_k(const int* __restrict__ src,
                                              const int* __restrict__ dst,
                                              const int* __restrict__ rowptr,
                                              int* __restrict__ cur,
                                              int* __restrict__ col) {
    int e = blockIdx.x * 256 + threadIdx.x;
    if (e >= NE) return;
    int d = dst[e];
    int pos = rowptr[d] + atomicAdd(&cur[d], 1);
    col[pos] = src[e];
}

// ---------------- GEMM: Hs = (X @ W) * dinv[row] ----------------
__global__ __launch_bounds__(256) void gemm128s_k(const float* __restrict__ X,
                                                  const float* __restrict__ W,
                                                  const float* __restrict__ dinv,
                                                  float* __restrict__ Hout) {
    __shared__ float xs[16][128];   // [k][row]
    __shared__ float ws[16][128];   // [k][col]
    const int tid = threadIdx.x;
    const int tx = tid & 15, ty = tid >> 4;
    const int rowBase = blockIdx.x * 128;

    float acc[8][8];
#pragma unroll
    for (int i = 0; i < 8; ++i)
#pragma unroll
        for (int j = 0; j < 8; ++j) acc[i][j] = 0.f;

    for (int k0 = 0; k0 < HD; k0 += 16) {
#pragma unroll
        for (int p = 0; p < 2; ++p) {
            int r  = (tid >> 2) + p * 64;
            int kk = (tid & 3) << 2;
            int grow = rowBase + r;
            float4 v = make_float4(0.f, 0.f, 0.f, 0.f);
            if (grow < NND) v = *(const float4*)(X + (size_t)grow * HD + k0 + kk);
            xs[kk + 0][r] = v.x;
            xs[kk + 1][r] = v.y;
            xs[kk + 2][r] = v.z;
            xs[kk + 3][r] = v.w;
        }
#pragma unroll
        for (int p = 0; p < 2; ++p) {
            int f  = tid + p * 256;
            int kk = f >> 5, cg = (f & 31) << 2;
            *(float4*)&ws[kk][cg] = *(const float4*)(W + (size_t)(k0 + kk) * HD + cg);
        }
        __syncthreads();
#pragma unroll
        for (int k = 0; k < 16; ++k) {
            float a[8], b[8];
            *(float4*)&a[0] = *(const float4*)&xs[k][ty * 8];
            *(float4*)&a[4] = *(const float4*)&xs[k][ty * 8 + 4];
            *(float4*)&b[0] = *(const float4*)&ws[k][tx * 8];
            *(float4*)&b[4] = *(const float4*)&ws[k][tx * 8 + 4];
#pragma unroll
            for (int i = 0; i < 8; ++i)
#pragma unroll
                for (int j = 0; j < 8; ++j)
                    acc[i][j] = fmaf(a[i], b[j], acc[i][j]);
        }
        __syncthreads();
    }
#pragma unroll
    for (int i = 0; i < 8; ++i) {
        int grow = rowBase + ty * 8 + i;
        if (grow < NND) {
            float di = dinv[grow];
            float4 o0 = make_float4(acc[i][0] * di, acc[i][1] * di, acc[i][2] * di, acc[i][3] * di);
            float4 o1 = make_float4(acc[i][4] * di, acc[i][5] * di, acc[i][6] * di, acc[i][7] * di);
            *(float4*)(Hout + (size_t)grow * HD + tx * 8)     = o0;
            *(float4*)(Hout + (size_t)grow * HD + tx * 8 + 4) = o1;
        }
    }
}

// ---------------- CSR aggregate + self + bias + ELU ----------------
__global__ __launch_bounds__(256) void agg_k(const float* __restrict__ Hs,
                                             const int* __restrict__ rowptr,
                                             const int* __restrict__ col,
                                             const float* __restrict__ dinv,
                                             const float* __restrict__ b,
                                             float* __restrict__ Out) {
    const int node = blockIdx.x * 8 + (threadIdx.x >> 5);
    if (node >= NND) return;
    const int lane = threadIdx.x & 31;

    float4 acc = *((const float4*)(Hs + (size_t)node * HD) + lane);   // self term
    const int e0 = rowptr[node], e1 = rowptr[node + 1];
    int e = e0;
    for (; e + 1 < e1; e += 2) {
        int s0 = col[e], s1 = col[e + 1];
        float4 v0 = *((const float4*)(Hs + (size_t)s0 * HD) + lane);
        float4 v1 = *((const float4*)(Hs + (size_t)s1 * HD) + lane);
        acc.x += v0.x + v1.x;
        acc.y += v0.y + v1.y;
        acc.z += v0.z + v1.z;
        acc.w += v0.w + v1.w;
    }
    if (e < e1) {
        int s0 = col[e];
        float4 v0 = *((const float4*)(Hs + (size_t)s0 * HD) + lane);
        acc.x += v0.x; acc.y += v0.y; acc.z += v0.z; acc.w += v0.w;
    }
    const float di = dinv[node];
    float4 b4 = ((const float4*)b)[lane];
    float r0 = fmaf(acc.x, di, b4.x);
    float r1 = fmaf(acc.y, di, b4.y);
    float r2 = fmaf(acc.z, di, b4.z);
    float r3 = fmaf(acc.w, di, b4.w);
    r0 = r0 > 0.f ? r0 : expm1f(r0);
    r1 = r1 > 0.f ? r1 : expm1f(r1);
    r2 = r2 > 0.f ? r2 : expm1f(r2);
    r3 = r3 > 0.f ? r3 : expm1f(r3);
    *((float4*)(Out + (size_t)node * HD) + lane) = make_float4(r0, r1, r2, r3);
}

// ---------------- output head: out = A @ Wo + bo ----------------
__global__ __launch_bounds__(256) void out_k(const float* __restrict__ A,
                                             const float* __restrict__ Wo,
                                             const float* __restrict__ bo,
                                             float* __restrict__ out) {
    int row  = blockIdx.x * 4 + (threadIdx.x >> 6);
    int lane = threadIdx.x & 63;
    if (row >= NND) return;
    float2 v = *(const float2*)(A + (size_t)row * HD + lane * 2);
    float2 w = *(const float2*)(Wo + lane * 2);
    float s = v.x * w.x + v.y * w.y;
#pragma unroll
    for (int off = 32; off > 0; off >>= 1) s += __shfl_down(s, off);
    if (lane == 0) out[row] = s + bo[0];
}

extern "C" void kernel_launch(void* const* d_in, const int* in_sizes, int n_in,
                              void* d_out, int out_size, void* d_ws, size_t ws_size,
                              hipStream_t stream) {
    const float* x   = (const float*)d_in[0];
    const int*   ei  = (const int*)d_in[1];
    const int*   src = ei;           // edge_index[0]
    const int*   dst = ei + NE;      // edge_index[1]
    const float* W0 = (const float*)d_in[2];
    const float* b0 = (const float*)d_in[3];
    const float* W1 = (const float*)d_in[4];
    const float* b1 = (const float*)d_in[5];
    const float* W2 = (const float*)d_in[6];
    const float* b2 = (const float*)d_in[7];
    const float* Wo = (const float*)d_in[8];
    const float* bo = (const float*)d_in[9];
    float* out = (float*)d_out;

    // workspace layout (256B-aligned chunks)
    float* dinv   = (float*)d_ws;                       // 102400 floats
    int*   cnt    = (int*)(dinv + 102400);              // 102400 ints
    int*   rowptr = cnt + 102400;                       // 102400 ints (NND+1 used)
    int*   bsum   = rowptr + 102400;                    // 128 ints (NSB used)
    int*   col    = bsum + 128;                         // 1000448 ints
    float* Hs     = (float*)(col + 1000448);            // NND*HD floats
    float* Ab     = Hs + (size_t)NND * HD;              // NND*HD floats

    // CSR build (per call; deterministic work)
    hipMemsetAsync(cnt, 0, NND * sizeof(int), stream);
    hist_k<<<(NE + 255) / 256, 256, 0, stream>>>(dst, cnt);
    dinv_k<<<(NND + 255) / 256, 256, 0, stream>>>(cnt, dinv);
    scan1_k<<<NSB, 256, 0, stream>>>(cnt, rowptr, bsum);
    scan2_k<<<1, 128, 0, stream>>>(bsum);
    scan3_k<<<NSB, 256, 0, stream>>>(rowptr, bsum);
    hipMemsetAsync(cnt, 0, NND * sizeof(int), stream);
    fill_k<<<(NE + 255) / 256, 256, 0, stream>>>(src, dst, rowptr, cnt, col);

    const float* Ws[3] = {W0, W1, W2};
    const float* bs[3] = {b0, b1, b2};
    const float* cur = x;
    for (int l = 0; l < 3; ++l) {
        gemm128s_k<<<(NND + 127) / 128, 256, 0, stream>>>(cur, Ws[l], dinv, Hs);
        agg_k<<<(NND + 7) / 8, 256, 0, stream>>>(Hs, rowptr, col, dinv, bs[l], Ab);
        cur = Ab;
    }
    out_k<<<(NND + 3) / 4, 256, 0, stream>>>(Ab, Wo, bo, out);
}

// Round 4
// 474.585 us; speedup vs baseline: 11.3111x; 1.1022x over previous
//
#include <hip/hip_runtime.h>
#include <hip/hip_fp16.h>
#include <math.h>

#define NND 100000
#define NE  1000000
#define HD  128
#define NSB 98   // scan blocks: ceil(NND/1024)

// ---------------- CSR build ----------------
__global__ __launch_bounds__(256) void hist_k(const int* __restrict__ dst,
                                              int* __restrict__ cnt) {
    int e = blockIdx.x * 256 + threadIdx.x;
    if (e < NE) atomicAdd(&cnt[dst[e]], 1);
}

__global__ __launch_bounds__(256) void dinv_k(const int* __restrict__ cnt,
                                              float* __restrict__ dinv) {
    int i = blockIdx.x * 256 + threadIdx.x;
    if (i < NND) dinv[i] = rsqrtf((float)cnt[i] + 1.0f);
}

// hierarchical exclusive scan: cnt[NND] -> rowptr[NND+1]
__global__ __launch_bounds__(256) void scan1_k(const int* __restrict__ cnt,
                                               int* __restrict__ rowptr,
                                               int* __restrict__ bsum) {
    __shared__ int ts[256];
    const int t = threadIdx.x, b = blockIdx.x;
    const int base = b * 1024 + t * 4;
    int4 v = make_int4(0, 0, 0, 0);
    if (base + 3 < NND) {
        v = *(const int4*)(cnt + base);
    } else if (base < NND) {
        v.x = cnt[base];
        if (base + 1 < NND) v.y = cnt[base + 1];
        if (base + 2 < NND) v.z = cnt[base + 2];
    }
    int s = v.x + v.y + v.z + v.w;
    ts[t] = s;
    __syncthreads();
    for (int off = 1; off < 256; off <<= 1) {
        int u = (t >= off) ? ts[t - off] : 0;
        __syncthreads();
        ts[t] += u;
        __syncthreads();
    }
    int ex = ts[t] - s;
    if (base < NND)     rowptr[base]     = ex;
    if (base + 1 < NND) rowptr[base + 1] = ex + v.x;
    if (base + 2 < NND) rowptr[base + 2] = ex + v.x + v.y;
    if (base + 3 < NND) rowptr[base + 3] = ex + v.x + v.y + v.z;
    if (t == 255) bsum[b] = ts[255];
}

__global__ __launch_bounds__(128) void scan2_k(int* __restrict__ bsum) {
    __shared__ int ts[128];
    const int t = threadIdx.x;
    int v = (t < NSB) ? bsum[t] : 0;
    ts[t] = v;
    __syncthreads();
    for (int off = 1; off < 128; off <<= 1) {
        int u = (t >= off) ? ts[t - off] : 0;
        __syncthreads();
        ts[t] += u;
        __syncthreads();
    }
    if (t < NSB) bsum[t] = ts[t] - v;
}

__global__ __launch_bounds__(256) void scan3_k(int* __restrict__ rowptr,
                                               const int* __restrict__ bsum) {
    const int b = blockIdx.x, t = threadIdx.x;
    const int off = bsum[b];
    const int base = b * 1024 + t * 4;
#pragma unroll
    for (int i = 0; i < 4; ++i) {
        int idx = base + i;
        if (idx < NND) rowptr[idx] += off;
    }
    if (b == 0 && t == 0) rowptr[NND] = NE;
}

__global__ __launch_bounds__(256) void fill_k(const int* __restrict__ src,
                                              const int* __restrict__ dst,
                                              const int* __restrict__ rowptr,
                                              int* __restrict__ cur,
                                              int* __restrict__ col) {
    int e = blockIdx.x * 256 + threadIdx.x;
    if (e >= NE) return;
    int d = dst[e];
    int pos = rowptr[d] + atomicAdd(&cur[d], 1);
    col[pos] = src[e];
}

// ---------------- GEMM: Hs = fp16((X @ W) * dinv[row]) ----------------
__global__ __launch_bounds__(256) void gemm128h_k(const float* __restrict__ X,
                                                  const float* __restrict__ W,
                                                  const float* __restrict__ dinv,
                                                  __half* __restrict__ Hout) {
    __shared__ float xs[16][128];
    __shared__ float ws[16][128];
    const int tid = threadIdx.x;
    const int tx = tid & 15, ty = tid >> 4;
    const int rowBase = blockIdx.x * 128;

    float acc[8][8];
#pragma unroll
    for (int i = 0; i < 8; ++i)
#pragma unroll
        for (int j = 0; j < 8; ++j) acc[i][j] = 0.f;

    for (int k0 = 0; k0 < HD; k0 += 16) {
#pragma unroll
        for (int p = 0; p < 2; ++p) {
            int r  = (tid >> 2) + p * 64;
            int kk = (tid & 3) << 2;
            int grow = rowBase + r;
            float4 v = make_float4(0.f, 0.f, 0.f, 0.f);
            if (grow < NND) v = *(const float4*)(X + (size_t)grow * HD + k0 + kk);
            xs[kk + 0][r] = v.x;
            xs[kk + 1][r] = v.y;
            xs[kk + 2][r] = v.z;
            xs[kk + 3][r] = v.w;
        }
#pragma unroll
        for (int p = 0; p < 2; ++p) {
            int f  = tid + p * 256;
            int kk = f >> 5, cg = (f & 31) << 2;
            *(float4*)&ws[kk][cg] = *(const float4*)(W + (size_t)(k0 + kk) * HD + cg);
        }
        __syncthreads();
#pragma unroll
        for (int k = 0; k < 16; ++k) {
            float a[8], b[8];
            *(float4*)&a[0] = *(const float4*)&xs[k][ty * 8];
            *(float4*)&a[4] = *(const float4*)&xs[k][ty * 8 + 4];
            *(float4*)&b[0] = *(const float4*)&ws[k][tx * 8];
            *(float4*)&b[4] = *(const float4*)&ws[k][tx * 8 + 4];
#pragma unroll
            for (int i = 0; i < 8; ++i)
#pragma unroll
                for (int j = 0; j < 8; ++j)
                    acc[i][j] = fmaf(a[i], b[j], acc[i][j]);
        }
        __syncthreads();
    }
#pragma unroll
    for (int i = 0; i < 8; ++i) {
        int grow = rowBase + ty * 8 + i;
        if (grow < NND) {
            float di = dinv[grow];
            __half2 h0 = __floats2half2_rn(acc[i][0] * di, acc[i][1] * di);
            __half2 h1 = __floats2half2_rn(acc[i][2] * di, acc[i][3] * di);
            __half2 h2 = __floats2half2_rn(acc[i][4] * di, acc[i][5] * di);
            __half2 h3 = __floats2half2_rn(acc[i][6] * di, acc[i][7] * di);
            uint4 st;
            st.x = *(unsigned int*)&h0;
            st.y = *(unsigned int*)&h1;
            st.z = *(unsigned int*)&h2;
            st.w = *(unsigned int*)&h3;
            *(uint4*)(Hout + (size_t)grow * HD + tx * 8) = st;
        }
    }
}

// ---------------- CSR aggregate (fp16 gather, fp32 accum) + ELU ----------------
// 32 lanes per node, 4 features (8 B) per lane.
__device__ __forceinline__ float4 gather_h4(const uint2* __restrict__ base,
                                            int row, int lane) {
    uint2 u = base[(size_t)row * 32 + lane];
    float2 f0 = __half22float2(*(__half2*)&u.x);
    float2 f1 = __half22float2(*(__half2*)&u.y);
    return make_float4(f0.x, f0.y, f1.x, f1.y);
}

__global__ __launch_bounds__(256) void agg_k(const __half* __restrict__ Hs,
                                             const int* __restrict__ rowptr,
                                             const int* __restrict__ col,
                                             const float* __restrict__ dinv,
                                             const float* __restrict__ b,
                                             float* __restrict__ Out) {
    const int node = blockIdx.x * 8 + (threadIdx.x >> 5);
    if (node >= NND) return;
    const int lane = threadIdx.x & 31;
    const uint2* base = (const uint2*)Hs;

    float4 acc = gather_h4(base, node, lane);   // self term
    const int e0 = rowptr[node], e1 = rowptr[node + 1];
    int e = e0;
    for (; e + 1 < e1; e += 2) {
        int s0 = col[e], s1 = col[e + 1];
        float4 v0 = gather_h4(base, s0, lane);
        float4 v1 = gather_h4(base, s1, lane);
        acc.x += v0.x + v1.x;
        acc.y += v0.y + v1.y;
        acc.z += v0.z + v1.z;
        acc.w += v0.w + v1.w;
    }
    if (e < e1) {
        float4 v0 = gather_h4(base, col[e], lane);
        acc.x += v0.x; acc.y += v0.y; acc.z += v0.z; acc.w += v0.w;
    }
    const float di = dinv[node];
    float4 b4 = ((const float4*)b)[lane];
    float r0 = fmaf(acc.x, di, b4.x);
    float r1 = fmaf(acc.y, di, b4.y);
    float r2 = fmaf(acc.z, di, b4.z);
    float r3 = fmaf(acc.w, di, b4.w);
    r0 = r0 > 0.f ? r0 : expm1f(r0);
    r1 = r1 > 0.f ? r1 : expm1f(r1);
    r2 = r2 > 0.f ? r2 : expm1f(r2);
    r3 = r3 > 0.f ? r3 : expm1f(r3);
    *((float4*)(Out + (size_t)node * HD) + lane) = make_float4(r0, r1, r2, r3);
}

// layer-3 variant: fused output head. out[node] = elu_row . Wo + bo
__global__ __launch_bounds__(256) void agg_out_k(const __half* __restrict__ Hs,
                                                 const int* __restrict__ rowptr,
                                                 const int* __restrict__ col,
                                                 const float* __restrict__ dinv,
                                                 const float* __restrict__ b,
                                                 const float* __restrict__ Wo,
                                                 const float* __restrict__ bo,
                                                 float* __restrict__ out) {
    const int node = blockIdx.x * 8 + (threadIdx.x >> 5);
    if (node >= NND) return;
    const int lane = threadIdx.x & 31;
    const uint2* base = (const uint2*)Hs;

    float4 acc = gather_h4(base, node, lane);
    const int e0 = rowptr[node], e1 = rowptr[node + 1];
    int e = e0;
    for (; e + 1 < e1; e += 2) {
        int s0 = col[e], s1 = col[e + 1];
        float4 v0 = gather_h4(base, s0, lane);
        float4 v1 = gather_h4(base, s1, lane);
        acc.x += v0.x + v1.x;
        acc.y += v0.y + v1.y;
        acc.z += v0.z + v1.z;
        acc.w += v0.w + v1.w;
    }
    if (e < e1) {
        float4 v0 = gather_h4(base, col[e], lane);
        acc.x += v0.x; acc.y += v0.y; acc.z += v0.z; acc.w += v0.w;
    }
    const float di = dinv[node];
    float4 b4 = ((const float4*)b)[lane];
    float r0 = fmaf(acc.x, di, b4.x);
    float r1 = fmaf(acc.y, di, b4.y);
    float r2 = fmaf(acc.z, di, b4.z);
    float r3 = fmaf(acc.w, di, b4.w);
    r0 = r0 > 0.f ? r0 : expm1f(r0);
    r1 = r1 > 0.f ? r1 : expm1f(r1);
    r2 = r2 > 0.f ? r2 : expm1f(r2);
    r3 = r3 > 0.f ? r3 : expm1f(r3);
    float4 w4 = ((const float4*)Wo)[lane];
    float s = r0 * w4.x + r1 * w4.y + r2 * w4.z + r3 * w4.w;
#pragma unroll
    for (int off = 16; off > 0; off >>= 1) s += __shfl_down(s, off, 32);
    if (lane == 0) out[node] = s + bo[0];
}

extern "C" void kernel_launch(void* const* d_in, const int* in_sizes, int n_in,
                              void* d_out, int out_size, void* d_ws, size_t ws_size,
                              hipStream_t stream) {
    const float* x   = (const float*)d_in[0];
    const int*   ei  = (const int*)d_in[1];
    const int*   src = ei;
    const int*   dst = ei + NE;
    const float* W0 = (const float*)d_in[2];
    const float* b0 = (const float*)d_in[3];
    const float* W1 = (const float*)d_in[4];
    const float* b1 = (const float*)d_in[5];
    const float* W2 = (const float*)d_in[6];
    const float* b2 = (const float*)d_in[7];
    const float* Wo = (const float*)d_in[8];
    const float* bo = (const float*)d_in[9];
    float* out = (float*)d_out;

    // workspace layout (256B-aligned chunks)
    float*  dinv   = (float*)d_ws;                     // 102400 floats
    int*    cnt    = (int*)(dinv + 102400);            // 102400 ints
    int*    rowptr = cnt + 102400;                     // 102400 ints
    int*    bsum   = rowptr + 102400;                  // 128 ints
    int*    col    = bsum + 128;                       // 1000448 ints
    __half* Hs     = (__half*)(col + 1000448);         // NND*HD halves (25.6 MB)
    float*  Ab     = (float*)(Hs + (size_t)NND * HD);  // NND*HD floats

    // CSR build
    hipMemsetAsync(cnt, 0, NND * sizeof(int), stream);
    hist_k<<<(NE + 255) / 256, 256, 0, stream>>>(dst, cnt);
    dinv_k<<<(NND + 255) / 256, 256, 0, stream>>>(cnt, dinv);
    scan1_k<<<NSB, 256, 0, stream>>>(cnt, rowptr, bsum);
    scan2_k<<<1, 128, 0, stream>>>(bsum);
    scan3_k<<<NSB, 256, 0, stream>>>(rowptr, bsum);
    hipMemsetAsync(cnt, 0, NND * sizeof(int), stream);
    fill_k<<<(NE + 255) / 256, 256, 0, stream>>>(src, dst, rowptr, cnt, col);

    // layer 1
    gemm128h_k<<<(NND + 127) / 128, 256, 0, stream>>>(x, W0, dinv, Hs);
    agg_k<<<(NND + 7) / 8, 256, 0, stream>>>(Hs, rowptr, col, dinv, b0, Ab);
    // layer 2
    gemm128h_k<<<(NND + 127) / 128, 256, 0, stream>>>(Ab, W1, dinv, Hs);
    agg_k<<<(NND + 7) / 8, 256, 0, stream>>>(Hs, rowptr, col, dinv, b1, Ab);
    // layer 3 + fused head
    gemm128h_k<<<(NND + 127) / 128, 256, 0, stream>>>(Ab, W2, dinv, Hs);
    agg_out_k<<<(NND + 7) / 8, 256, 0, stream>>>(Hs, rowptr, col, dinv, b2, Wo, bo, out);
}

// Round 5
// 338.519 us; speedup vs baseline: 15.8576x; 1.4019x over previous
//
#include <hip/hip_runtime.h>
#include <hip/hip_fp16.h>
#include <math.h>

#define NND 100000
#define NE  1000000
#define HD  128
#define NSB 98   // scan blocks: ceil(NND/1024)

typedef _Float16 f16x8 __attribute__((ext_vector_type(8)));
typedef float f32x4 __attribute__((ext_vector_type(4)));

// ---------------- CSR build ----------------
__global__ __launch_bounds__(256) void hist_k(const int* __restrict__ dst,
                                              int* __restrict__ cnt) {
    int e = blockIdx.x * 256 + threadIdx.x;
    if (e < NE) atomicAdd(&cnt[dst[e]], 1);
}

__global__ __launch_bounds__(256) void dinv_k(const int* __restrict__ cnt,
                                              float* __restrict__ dinv) {
    int i = blockIdx.x * 256 + threadIdx.x;
    if (i < NND) dinv[i] = rsqrtf((float)cnt[i] + 1.0f);
}

__global__ __launch_bounds__(256) void scan1_k(const int* __restrict__ cnt,
                                               int* __restrict__ rowptr,
                                               int* __restrict__ bsum) {
    __shared__ int ts[256];
    const int t = threadIdx.x, b = blockIdx.x;
    const int base = b * 1024 + t * 4;
    int4 v = make_int4(0, 0, 0, 0);
    if (base + 3 < NND) {
        v = *(const int4*)(cnt + base);
    } else if (base < NND) {
        v.x = cnt[base];
        if (base + 1 < NND) v.y = cnt[base + 1];
        if (base + 2 < NND) v.z = cnt[base + 2];
    }
    int s = v.x + v.y + v.z + v.w;
    ts[t] = s;
    __syncthreads();
    for (int off = 1; off < 256; off <<= 1) {
        int u = (t >= off) ? ts[t - off] : 0;
        __syncthreads();
        ts[t] += u;
        __syncthreads();
    }
    int ex = ts[t] - s;
    if (base < NND)     rowptr[base]     = ex;
    if (base + 1 < NND) rowptr[base + 1] = ex + v.x;
    if (base + 2 < NND) rowptr[base + 2] = ex + v.x + v.y;
    if (base + 3 < NND) rowptr[base + 3] = ex + v.x + v.y + v.z;
    if (t == 255) bsum[b] = ts[255];
}

__global__ __launch_bounds__(128) void scan2_k(int* __restrict__ bsum) {
    __shared__ int ts[128];
    const int t = threadIdx.x;
    int v = (t < NSB) ? bsum[t] : 0;
    ts[t] = v;
    __syncthreads();
    for (int off = 1; off < 128; off <<= 1) {
        int u = (t >= off) ? ts[t - off] : 0;
        __syncthreads();
        ts[t] += u;
        __syncthreads();
    }
    if (t < NSB) bsum[t] = ts[t] - v;
}

__global__ __launch_bounds__(256) void scan3_k(int* __restrict__ rowptr,
                                               const int* __restrict__ bsum) {
    const int b = blockIdx.x, t = threadIdx.x;
    const int off = bsum[b];
    const int base = b * 1024 + t * 4;
#pragma unroll
    for (int i = 0; i < 4; ++i) {
        int idx = base + i;
        if (idx < NND) rowptr[idx] += off;
    }
    if (b == 0 && t == 0) rowptr[NND] = NE;
}

__global__ __launch_bounds__(256) void fill_k(const int* __restrict__ src,
                                              const int* __restrict__ dst,
                                              const int* __restrict__ rowptr,
                                              int* __restrict__ cur,
                                              int* __restrict__ col) {
    int e = blockIdx.x * 256 + threadIdx.x;
    if (e >= NE) return;
    int d = dst[e];
    int pos = rowptr[d] + atomicAdd(&cur[d], 1);
    col[pos] = src[e];
}

// ---------------- weight preconvert: WT[m][n][k] = fp16(W_m[k][n]) ----------------
__global__ __launch_bounds__(256) void wcvt_k(const float* __restrict__ W0,
                                              const float* __restrict__ W1,
                                              const float* __restrict__ W2,
                                              __half* __restrict__ WT) {
    int i = blockIdx.x * 256 + threadIdx.x;   // 3*128*128
    if (i >= 3 * HD * HD) return;
    int m = i / (HD * HD), r = i % (HD * HD);
    int n = r / HD, k = r % HD;
    const float* W = (m == 0) ? W0 : (m == 1) ? W1 : W2;
    WT[i] = __float2half(W[k * HD + n]);
}

// ---------------- MFMA GEMM: Hs = fp16(dinv[row] * (A @ W)) ----------------
// Swapped operands: A-frag from WT (feat x k), B-frag from node rows (k x node).
// D tile: col(lane&15)=node, row((lane>>4)*4+reg)=feat -> 8B stores per lane.
// 4 waves/block, 32 nodes/wave -> 128 nodes/block.
template<bool A_HALF>
__global__ __launch_bounds__(256) void gemm_mfma_k(const void* __restrict__ Ain,
                                                   const __half* __restrict__ WT,
                                                   const float* __restrict__ dinv,
                                                   __half* __restrict__ Hout) {
    const int wave = threadIdx.x >> 6;
    const int lane = threadIdx.x & 63;
    const int l15 = lane & 15, g = lane >> 4;
    const int nodeBase = blockIdx.x * 128 + wave * 32;
    if (nodeBase >= NND) return;

    f32x4 acc[2][8];
#pragma unroll
    for (int nt = 0; nt < 2; ++nt)
#pragma unroll
        for (int ft = 0; ft < 8; ++ft) acc[nt][ft] = (f32x4)0.f;

#pragma unroll
    for (int chunk = 0; chunk < 4; ++chunk) {
        const int k0 = chunk * 32 + g * 8;
        f16x8 aw[8];
#pragma unroll
        for (int ft = 0; ft < 8; ++ft)
            aw[ft] = *(const f16x8*)(WT + (size_t)(ft * 16 + l15) * HD + k0);
        f16x8 bx[2];
#pragma unroll
        for (int nt = 0; nt < 2; ++nt) {
            int node = nodeBase + nt * 16 + l15;
            node = node < NND ? node : NND - 1;
            if (A_HALF) {
                bx[nt] = *(const f16x8*)((const __half*)Ain + (size_t)node * HD + k0);
            } else {
                const float* p = (const float*)Ain + (size_t)node * HD + k0;
                float4 lo = *(const float4*)p;
                float4 hi = *(const float4*)(p + 4);
                f16x8 t;
                t[0] = (_Float16)lo.x; t[1] = (_Float16)lo.y;
                t[2] = (_Float16)lo.z; t[3] = (_Float16)lo.w;
                t[4] = (_Float16)hi.x; t[5] = (_Float16)hi.y;
                t[6] = (_Float16)hi.z; t[7] = (_Float16)hi.w;
                bx[nt] = t;
            }
        }
#pragma unroll
        for (int nt = 0; nt < 2; ++nt)
#pragma unroll
            for (int ft = 0; ft < 8; ++ft)
                acc[nt][ft] = __builtin_amdgcn_mfma_f32_16x16x32_f16(aw[ft], bx[nt], acc[nt][ft], 0, 0, 0);
    }

#pragma unroll
    for (int nt = 0; nt < 2; ++nt) {
        const int node = nodeBase + nt * 16 + l15;
        if (node >= NND) continue;
        const float di = dinv[node];
#pragma unroll
        for (int ft = 0; ft < 8; ++ft) {
            __half2 p0 = __floats2half2_rn(acc[nt][ft][0] * di, acc[nt][ft][1] * di);
            __half2 p1 = __floats2half2_rn(acc[nt][ft][2] * di, acc[nt][ft][3] * di);
            uint2 st;
            st.x = *(unsigned int*)&p0;
            st.y = *(unsigned int*)&p1;
            *(uint2*)(Hout + (size_t)node * HD + ft * 16 + g * 4) = st;
        }
    }
}

// ---------------- CSR aggregate (fp16 gather, fp32 accum) ----------------
__device__ __forceinline__ float4 gather_h4(const uint2* __restrict__ base,
                                            int row, int lane) {
    uint2 u = base[(size_t)row * 32 + lane];
    float2 f0 = __half22float2(*(__half2*)&u.x);
    float2 f1 = __half22float2(*(__half2*)&u.y);
    return make_float4(f0.x, f0.y, f1.x, f1.y);
}

// layers 1-2: fp16 output (feeds next GEMM)
__global__ __launch_bounds__(256) void agg_k(const __half* __restrict__ Hs,
                                             const int* __restrict__ rowptr,
                                             const int* __restrict__ col,
                                             const float* __restrict__ dinv,
                                             const float* __restrict__ b,
                                             __half* __restrict__ Out) {
    const int node = blockIdx.x * 8 + (threadIdx.x >> 5);
    if (node >= NND) return;
    const int lane = threadIdx.x & 31;
    const uint2* base = (const uint2*)Hs;

    float4 acc = gather_h4(base, node, lane);   // self term
    const int e0 = rowptr[node], e1 = rowptr[node + 1];
    int e = e0;
    for (; e + 3 < e1; e += 4) {
        int s0 = col[e], s1 = col[e + 1], s2 = col[e + 2], s3 = col[e + 3];
        float4 v0 = gather_h4(base, s0, lane);
        float4 v1 = gather_h4(base, s1, lane);
        float4 v2 = gather_h4(base, s2, lane);
        float4 v3 = gather_h4(base, s3, lane);
        acc.x += (v0.x + v1.x) + (v2.x + v3.x);
        acc.y += (v0.y + v1.y) + (v2.y + v3.y);
        acc.z += (v0.z + v1.z) + (v2.z + v3.z);
        acc.w += (v0.w + v1.w) + (v2.w + v3.w);
    }
    for (; e < e1; ++e) {
        float4 v0 = gather_h4(base, col[e], lane);
        acc.x += v0.x; acc.y += v0.y; acc.z += v0.z; acc.w += v0.w;
    }
    const float di = dinv[node];
    float4 b4 = ((const float4*)b)[lane];
    float r0 = fmaf(acc.x, di, b4.x);
    float r1 = fmaf(acc.y, di, b4.y);
    float r2 = fmaf(acc.z, di, b4.z);
    float r3 = fmaf(acc.w, di, b4.w);
    r0 = r0 > 0.f ? r0 : expm1f(r0);
    r1 = r1 > 0.f ? r1 : expm1f(r1);
    r2 = r2 > 0.f ? r2 : expm1f(r2);
    r3 = r3 > 0.f ? r3 : expm1f(r3);
    __half2 p0 = __floats2half2_rn(r0, r1);
    __half2 p1 = __floats2half2_rn(r2, r3);
    uint2 st;
    st.x = *(unsigned int*)&p0;
    st.y = *(unsigned int*)&p1;
    ((uint2*)Out)[(size_t)node * 32 + lane] = st;
}

// layer 3: fused output head. out[node] = elu_row . Wo + bo
__global__ __launch_bounds__(256) void agg_out_k(const __half* __restrict__ Hs,
                                                 const int* __restrict__ rowptr,
                                                 const int* __restrict__ col,
                                                 const float* __restrict__ dinv,
                                                 const float* __restrict__ b,
                                                 const float* __restrict__ Wo,
                                                 const float* __restrict__ bo,
                                                 float* __restrict__ out) {
    const int node = blockIdx.x * 8 + (threadIdx.x >> 5);
    if (node >= NND) return;
    const int lane = threadIdx.x & 31;
    const uint2* base = (const uint2*)Hs;

    float4 acc = gather_h4(base, node, lane);
    const int e0 = rowptr[node], e1 = rowptr[node + 1];
    int e = e0;
    for (; e + 3 < e1; e += 4) {
        int s0 = col[e], s1 = col[e + 1], s2 = col[e + 2], s3 = col[e + 3];
        float4 v0 = gather_h4(base, s0, lane);
        float4 v1 = gather_h4(base, s1, lane);
        float4 v2 = gather_h4(base, s2, lane);
        float4 v3 = gather_h4(base, s3, lane);
        acc.x += (v0.x + v1.x) + (v2.x + v3.x);
        acc.y += (v0.y + v1.y) + (v2.y + v3.y);
        acc.z += (v0.z + v1.z) + (v2.z + v3.z);
        acc.w += (v0.w + v1.w) + (v2.w + v3.w);
    }
    for (; e < e1; ++e) {
        float4 v0 = gather_h4(base, col[e], lane);
        acc.x += v0.x; acc.y += v0.y; acc.z += v0.z; acc.w += v0.w;
    }
    const float di = dinv[node];
    float4 b4 = ((const float4*)b)[lane];
    float r0 = fmaf(acc.x, di, b4.x);
    float r1 = fmaf(acc.y, di, b4.y);
    float r2 = fmaf(acc.z, di, b4.z);
    float r3 = fmaf(acc.w, di, b4.w);
    r0 = r0 > 0.f ? r0 : expm1f(r0);
    r1 = r1 > 0.f ? r1 : expm1f(r1);
    r2 = r2 > 0.f ? r2 : expm1f(r2);
    r3 = r3 > 0.f ? r3 : expm1f(r3);
    float4 w4 = ((const float4*)Wo)[lane];
    float s = r0 * w4.x + r1 * w4.y + r2 * w4.z + r3 * w4.w;
#pragma unroll
    for (int off = 16; off > 0; off >>= 1) s += __shfl_down(s, off, 32);
    if (lane == 0) out[node] = s + bo[0];
}

extern "C" void kernel_launch(void* const* d_in, const int* in_sizes, int n_in,
                              void* d_out, int out_size, void* d_ws, size_t ws_size,
                              hipStream_t stream) {
    const float* x   = (const float*)d_in[0];
    const int*   ei  = (const int*)d_in[1];
    const int*   src = ei;
    const int*   dst = ei + NE;
    const float* W0 = (const float*)d_in[2];
    const float* b0 = (const float*)d_in[3];
    const float* W1 = (const float*)d_in[4];
    const float* b1 = (const float*)d_in[5];
    const float* W2 = (const float*)d_in[6];
    const float* b2 = (const float*)d_in[7];
    const float* Wo = (const float*)d_in[8];
    const float* bo = (const float*)d_in[9];
    float* out = (float*)d_out;

    // workspace layout (256B-aligned chunks)
    float*  dinv   = (float*)d_ws;                      // 102400 floats
    int*    cnt    = (int*)(dinv + 102400);             // 102400 ints
    int*    rowptr = cnt + 102400;                      // 102400 ints
    int*    bsum   = rowptr + 102400;                   // 128 ints
    int*    col    = bsum + 128;                        // 1000448 ints
    __half* WT     = (__half*)(col + 1000448);          // 3*16384 halves
    __half* Hs     = WT + 3 * HD * HD;                  // NND*HD halves
    __half* Abh    = Hs + (size_t)NND * HD;             // NND*HD halves

    // CSR build
    hipMemsetAsync(cnt, 0, NND * sizeof(int), stream);
    hist_k<<<(NE + 255) / 256, 256, 0, stream>>>(dst, cnt);
    dinv_k<<<(NND + 255) / 256, 256, 0, stream>>>(cnt, dinv);
    scan1_k<<<NSB, 256, 0, stream>>>(cnt, rowptr, bsum);
    scan2_k<<<1, 128, 0, stream>>>(bsum);
    scan3_k<<<NSB, 256, 0, stream>>>(rowptr, bsum);
    hipMemsetAsync(cnt, 0, NND * sizeof(int), stream);
    fill_k<<<(NE + 255) / 256, 256, 0, stream>>>(src, dst, rowptr, cnt, col);
    wcvt_k<<<(3 * HD * HD + 255) / 256, 256, 0, stream>>>(W0, W1, W2, WT);

    const int GB = (NND + 127) / 128;   // 782
    // layer 1 (fp32 input)
    gemm_mfma_k<false><<<GB, 256, 0, stream>>>(x, WT, dinv, Hs);
    agg_k<<<(NND + 7) / 8, 256, 0, stream>>>(Hs, rowptr, col, dinv, b0, Abh);
    // layer 2 (fp16 input)
    gemm_mfma_k<true><<<GB, 256, 0, stream>>>(Abh, WT + HD * HD, dinv, Hs);
    agg_k<<<(NND + 7) / 8, 256, 0, stream>>>(Hs, rowptr, col, dinv, b1, Abh);
    // layer 3 + fused head
    gemm_mfma_k<true><<<GB, 256, 0, stream>>>(Abh, WT + 2 * HD * HD, dinv, Hs);
    agg_out_k<<<(NND + 7) / 8, 256, 0, stream>>>(Hs, rowptr, col, dinv, b2, Wo, bo, out);
}

// Round 6
// 300.041 us; speedup vs baseline: 17.8912x; 1.1282x over previous
//
#include <hip/hip_runtime.h>
#include <hip/hip_fp16.h>
#include <math.h>

#define NND 100000
#define NE  1000000
#define HD  128
#define NSB 98   // scan blocks: ceil(NND/1024)

typedef _Float16 f16x8 __attribute__((ext_vector_type(8)));
typedef float f32x4 __attribute__((ext_vector_type(4)));

// ---------------- CSR build (2-pass, atomics only in pass1) ----------------
__global__ __launch_bounds__(256) void pass1_k(const int* __restrict__ dst,
                                               int* __restrict__ cnt,
                                               int* __restrict__ rel) {
    int e = blockIdx.x * 256 + threadIdx.x;
    if (e < NE) rel[e] = atomicAdd(&cnt[dst[e]], 1);
}

// exclusive scan of cnt -> rowptr, fused dinv = rsqrt(cnt+1)
__global__ __launch_bounds__(256) void scan1_k(const int* __restrict__ cnt,
                                               int* __restrict__ rowptr,
                                               int* __restrict__ bsum,
                                               float* __restrict__ dinv) {
    __shared__ int ts[256];
    const int t = threadIdx.x, b = blockIdx.x;
    const int base = b * 1024 + t * 4;
    int4 v = make_int4(0, 0, 0, 0);
    if (base + 3 < NND) {
        v = *(const int4*)(cnt + base);
    } else if (base < NND) {
        v.x = cnt[base];
        if (base + 1 < NND) v.y = cnt[base + 1];
        if (base + 2 < NND) v.z = cnt[base + 2];
    }
    int s = v.x + v.y + v.z + v.w;
    ts[t] = s;
    __syncthreads();
    for (int off = 1; off < 256; off <<= 1) {
        int u = (t >= off) ? ts[t - off] : 0;
        __syncthreads();
        ts[t] += u;
        __syncthreads();
    }
    int ex = ts[t] - s;
    if (base < NND)     { rowptr[base]     = ex;                     dinv[base]     = rsqrtf((float)v.x + 1.f); }
    if (base + 1 < NND) { rowptr[base + 1] = ex + v.x;               dinv[base + 1] = rsqrtf((float)v.y + 1.f); }
    if (base + 2 < NND) { rowptr[base + 2] = ex + v.x + v.y;         dinv[base + 2] = rsqrtf((float)v.z + 1.f); }
    if (base + 3 < NND) { rowptr[base + 3] = ex + v.x + v.y + v.z;   dinv[base + 3] = rsqrtf((float)v.w + 1.f); }
    if (t == 255) bsum[b] = ts[255];
}

__global__ __launch_bounds__(128) void scan2_k(int* __restrict__ bsum) {
    __shared__ int ts[128];
    const int t = threadIdx.x;
    int v = (t < NSB) ? bsum[t] : 0;
    ts[t] = v;
    __syncthreads();
    for (int off = 1; off < 128; off <<= 1) {
        int u = (t >= off) ? ts[t - off] : 0;
        __syncthreads();
        ts[t] += u;
        __syncthreads();
    }
    if (t < NSB) bsum[t] = ts[t] - v;
}

__global__ __launch_bounds__(256) void scan3_k(int* __restrict__ rowptr,
                                               const int* __restrict__ bsum) {
    const int b = blockIdx.x, t = threadIdx.x;
    const int off = bsum[b];
    const int base = b * 1024 + t * 4;
#pragma unroll
    for (int i = 0; i < 4; ++i) {
        int idx = base + i;
        if (idx < NND) rowptr[idx] += off;
    }
    if (b == 0 && t == 0) rowptr[NND] = NE;
}

// scatter col without atomics: pos = rowptr[dst] + rel
__global__ __launch_bounds__(256) void pass2_k(const int* __restrict__ src,
                                               const int* __restrict__ dst,
                                               const int* __restrict__ rel,
                                               const int* __restrict__ rowptr,
                                               int* __restrict__ col) {
    int e = blockIdx.x * 256 + threadIdx.x;
    if (e >= NE) return;
    int d = dst[e];
    col[rowptr[d] + rel[e]] = src[e];
}

// ---------------- weight preconvert: WT[m][n][k] = fp16(W_m[k][n]) ----------------
__global__ __launch_bounds__(256) void wcvt_k(const float* __restrict__ W0,
                                              const float* __restrict__ W1,
                                              const float* __restrict__ W2,
                                              __half* __restrict__ WT) {
    int i = blockIdx.x * 256 + threadIdx.x;   // 3*128*128
    if (i >= 3 * HD * HD) return;
    int m = i / (HD * HD), r = i % (HD * HD);
    int n = r / HD, k = r % HD;
    const float* W = (m == 0) ? W0 : (m == 1) ? W1 : W2;
    WT[i] = __float2half(W[k * HD + n]);
}

// ---------------- MFMA GEMM: Hs = fp16(dinv[row] * (A @ W)) ----------------
template<bool A_HALF>
__global__ __launch_bounds__(256) void gemm_mfma_k(const void* __restrict__ Ain,
                                                   const __half* __restrict__ WT,
                                                   const float* __restrict__ dinv,
                                                   __half* __restrict__ Hout) {
    const int wave = threadIdx.x >> 6;
    const int lane = threadIdx.x & 63;
    const int l15 = lane & 15, g = lane >> 4;
    const int nodeBase = blockIdx.x * 128 + wave * 32;
    if (nodeBase >= NND) return;

    f32x4 acc[2][8];
#pragma unroll
    for (int nt = 0; nt < 2; ++nt)
#pragma unroll
        for (int ft = 0; ft < 8; ++ft) acc[nt][ft] = (f32x4)0.f;

#pragma unroll
    for (int chunk = 0; chunk < 4; ++chunk) {
        const int k0 = chunk * 32 + g * 8;
        f16x8 aw[8];
#pragma unroll
        for (int ft = 0; ft < 8; ++ft)
            aw[ft] = *(const f16x8*)(WT + (size_t)(ft * 16 + l15) * HD + k0);
        f16x8 bx[2];
#pragma unroll
        for (int nt = 0; nt < 2; ++nt) {
            int node = nodeBase + nt * 16 + l15;
            node = node < NND ? node : NND - 1;
            if (A_HALF) {
                bx[nt] = *(const f16x8*)((const __half*)Ain + (size_t)node * HD + k0);
            } else {
                const float* p = (const float*)Ain + (size_t)node * HD + k0;
                float4 lo = *(const float4*)p;
                float4 hi = *(const float4*)(p + 4);
                f16x8 t;
                t[0] = (_Float16)lo.x; t[1] = (_Float16)lo.y;
                t[2] = (_Float16)lo.z; t[3] = (_Float16)lo.w;
                t[4] = (_Float16)hi.x; t[5] = (_Float16)hi.y;
                t[6] = (_Float16)hi.z; t[7] = (_Float16)hi.w;
                bx[nt] = t;
            }
        }
#pragma unroll
        for (int nt = 0; nt < 2; ++nt)
#pragma unroll
            for (int ft = 0; ft < 8; ++ft)
                acc[nt][ft] = __builtin_amdgcn_mfma_f32_16x16x32_f16(aw[ft], bx[nt], acc[nt][ft], 0, 0, 0);
    }

#pragma unroll
    for (int nt = 0; nt < 2; ++nt) {
        const int node = nodeBase + nt * 16 + l15;
        if (node >= NND) continue;
        const float di = dinv[node];
#pragma unroll
        for (int ft = 0; ft < 8; ++ft) {
            __half2 p0 = __floats2half2_rn(acc[nt][ft][0] * di, acc[nt][ft][1] * di);
            __half2 p1 = __floats2half2_rn(acc[nt][ft][2] * di, acc[nt][ft][3] * di);
            uint2 st;
            st.x = *(unsigned int*)&p0;
            st.y = *(unsigned int*)&p1;
            *(uint2*)(Hout + (size_t)node * HD + ft * 16 + g * 4) = st;
        }
    }
}

// ---------------- CSR aggregate: 16 lanes/node, uint4 (16B) per lane ----------------
__device__ __forceinline__ void acc_add(float* acc, uint4 u) {
    float2 f0 = __half22float2(*(__half2*)&u.x);
    float2 f1 = __half22float2(*(__half2*)&u.y);
    float2 f2 = __half22float2(*(__half2*)&u.z);
    float2 f3 = __half22float2(*(__half2*)&u.w);
    acc[0] += f0.x; acc[1] += f0.y; acc[2] += f1.x; acc[3] += f1.y;
    acc[4] += f2.x; acc[5] += f2.y; acc[6] += f3.x; acc[7] += f3.y;
}

// layers 1-2: fp16 output (feeds next GEMM)
__global__ __launch_bounds__(256) void agg_k(const __half* __restrict__ Hs,
                                             const int* __restrict__ rowptr,
                                             const int* __restrict__ col,
                                             const float* __restrict__ dinv,
                                             const float* __restrict__ b,
                                             __half* __restrict__ Out) {
    const int node = blockIdx.x * 16 + (threadIdx.x >> 4);
    if (node >= NND) return;
    const int lane = threadIdx.x & 15;
    const uint4* base = (const uint4*)Hs;   // 16 uint4 per row

    float acc[8] = {0.f, 0.f, 0.f, 0.f, 0.f, 0.f, 0.f, 0.f};
    acc_add(acc, base[(size_t)node * 16 + lane]);   // self term
    const int e0 = rowptr[node], e1 = rowptr[node + 1];
    int e = e0;
    for (; e + 7 < e1; e += 8) {
        uint4 v[8];
#pragma unroll
        for (int i = 0; i < 8; ++i) v[i] = base[(size_t)col[e + i] * 16 + lane];
#pragma unroll
        for (int i = 0; i < 8; ++i) acc_add(acc, v[i]);
    }
    for (; e + 1 < e1; e += 2) {
        uint4 v0 = base[(size_t)col[e] * 16 + lane];
        uint4 v1 = base[(size_t)col[e + 1] * 16 + lane];
        acc_add(acc, v0);
        acc_add(acc, v1);
    }
    if (e < e1) acc_add(acc, base[(size_t)col[e] * 16 + lane]);

    const float di = dinv[node];
    float4 b0 = ((const float4*)b)[lane * 2];
    float4 b1 = ((const float4*)b)[lane * 2 + 1];
    float r[8];
    r[0] = fmaf(acc[0], di, b0.x); r[1] = fmaf(acc[1], di, b0.y);
    r[2] = fmaf(acc[2], di, b0.z); r[3] = fmaf(acc[3], di, b0.w);
    r[4] = fmaf(acc[4], di, b1.x); r[5] = fmaf(acc[5], di, b1.y);
    r[6] = fmaf(acc[6], di, b1.z); r[7] = fmaf(acc[7], di, b1.w);
#pragma unroll
    for (int i = 0; i < 8; ++i) r[i] = r[i] > 0.f ? r[i] : expm1f(r[i]);
    __half2 p0 = __floats2half2_rn(r[0], r[1]);
    __half2 p1 = __floats2half2_rn(r[2], r[3]);
    __half2 p2 = __floats2half2_rn(r[4], r[5]);
    __half2 p3 = __floats2half2_rn(r[6], r[7]);
    uint4 st;
    st.x = *(unsigned int*)&p0; st.y = *(unsigned int*)&p1;
    st.z = *(unsigned int*)&p2; st.w = *(unsigned int*)&p3;
    ((uint4*)Out)[(size_t)node * 16 + lane] = st;
}

// layer 3: fused output head. out[node] = elu_row . Wo + bo
__global__ __launch_bounds__(256) void agg_out_k(const __half* __restrict__ Hs,
                                                 const int* __restrict__ rowptr,
                                                 const int* __restrict__ col,
                                                 const float* __restrict__ dinv,
                                                 const float* __restrict__ b,
                                                 const float* __restrict__ Wo,
                                                 const float* __restrict__ bo,
                                                 float* __restrict__ out) {
    const int node = blockIdx.x * 16 + (threadIdx.x >> 4);
    if (node >= NND) return;
    const int lane = threadIdx.x & 15;
    const uint4* base = (const uint4*)Hs;

    float acc[8] = {0.f, 0.f, 0.f, 0.f, 0.f, 0.f, 0.f, 0.f};
    acc_add(acc, base[(size_t)node * 16 + lane]);
    const int e0 = rowptr[node], e1 = rowptr[node + 1];
    int e = e0;
    for (; e + 7 < e1; e += 8) {
        uint4 v[8];
#pragma unroll
        for (int i = 0; i < 8; ++i) v[i] = base[(size_t)col[e + i] * 16 + lane];
#pragma unroll
        for (int i = 0; i < 8; ++i) acc_add(acc, v[i]);
    }
    for (; e + 1 < e1; e += 2) {
        uint4 v0 = base[(size_t)col[e] * 16 + lane];
        uint4 v1 = base[(size_t)col[e + 1] * 16 + lane];
        acc_add(acc, v0);
        acc_add(acc, v1);
    }
    if (e < e1) acc_add(acc, base[(size_t)col[e] * 16 + lane]);

    const float di = dinv[node];
    float4 b0 = ((const float4*)b)[lane * 2];
    float4 b1 = ((const float4*)b)[lane * 2 + 1];
    float r[8];
    r[0] = fmaf(acc[0], di, b0.x); r[1] = fmaf(acc[1], di, b0.y);
    r[2] = fmaf(acc[2], di, b0.z); r[3] = fmaf(acc[3], di, b0.w);
    r[4] = fmaf(acc[4], di, b1.x); r[5] = fmaf(acc[5], di, b1.y);
    r[6] = fmaf(acc[6], di, b1.z); r[7] = fmaf(acc[7], di, b1.w);
#pragma unroll
    for (int i = 0; i < 8; ++i) r[i] = r[i] > 0.f ? r[i] : expm1f(r[i]);
    float4 w0 = ((const float4*)Wo)[lane * 2];
    float4 w1 = ((const float4*)Wo)[lane * 2 + 1];
    float s = r[0] * w0.x + r[1] * w0.y + r[2] * w0.z + r[3] * w0.w
            + r[4] * w1.x + r[5] * w1.y + r[6] * w1.z + r[7] * w1.w;
#pragma unroll
    for (int off = 8; off > 0; off >>= 1) s += __shfl_down(s, off, 16);
    if (lane == 0) out[node] = s + bo[0];
}

extern "C" void kernel_launch(void* const* d_in, const int* in_sizes, int n_in,
                              void* d_out, int out_size, void* d_ws, size_t ws_size,
                              hipStream_t stream) {
    const float* x   = (const float*)d_in[0];
    const int*   ei  = (const int*)d_in[1];
    const int*   src = ei;
    const int*   dst = ei + NE;
    const float* W0 = (const float*)d_in[2];
    const float* b0 = (const float*)d_in[3];
    const float* W1 = (const float*)d_in[4];
    const float* b1 = (const float*)d_in[5];
    const float* W2 = (const float*)d_in[6];
    const float* b2 = (const float*)d_in[7];
    const float* Wo = (const float*)d_in[8];
    const float* bo = (const float*)d_in[9];
    float* out = (float*)d_out;

    // workspace layout (256B-aligned chunks)
    float*  dinv   = (float*)d_ws;                      // 102400 floats
    int*    cnt    = (int*)(dinv + 102400);             // 102400 ints
    int*    rowptr = cnt + 102400;                      // 102400 ints
    int*    bsum   = rowptr + 102400;                   // 128 ints
    int*    col    = bsum + 128;                        // 1000448 ints
    int*    rel    = col + 1000448;                     // 1000448 ints
    __half* WT     = (__half*)(rel + 1000448);          // 3*16384 halves
    __half* Hs     = WT + 3 * HD * HD;                  // NND*HD halves
    __half* Abh    = Hs + (size_t)NND * HD;             // NND*HD halves

    // CSR build
    hipMemsetAsync(cnt, 0, NND * sizeof(int), stream);
    pass1_k<<<(NE + 255) / 256, 256, 0, stream>>>(dst, cnt, rel);
    scan1_k<<<NSB, 256, 0, stream>>>(cnt, rowptr, bsum, dinv);
    scan2_k<<<1, 128, 0, stream>>>(bsum);
    scan3_k<<<NSB, 256, 0, stream>>>(rowptr, bsum);
    pass2_k<<<(NE + 255) / 256, 256, 0, stream>>>(src, dst, rel, rowptr, col);
    wcvt_k<<<(3 * HD * HD + 255) / 256, 256, 0, stream>>>(W0, W1, W2, WT);

    const int GB = (NND + 127) / 128;   // 782
    const int AB = (NND + 15) / 16;     // 6250
    // layer 1 (fp32 input)
    gemm_mfma_k<false><<<GB, 256, 0, stream>>>(x, WT, dinv, Hs);
    agg_k<<<AB, 256, 0, stream>>>(Hs, rowptr, col, dinv, b0, Abh);
    // layer 2 (fp16 input)
    gemm_mfma_k<true><<<GB, 256, 0, stream>>>(Abh, WT + HD * HD, dinv, Hs);
    agg_k<<<AB, 256, 0, stream>>>(Hs, rowptr, col, dinv, b1, Abh);
    // layer 3 + fused head
    gemm_mfma_k<true><<<GB, 256, 0, stream>>>(Abh, WT + 2 * HD * HD, dinv, Hs);
    agg_out_k<<<AB, 256, 0, stream>>>(Hs, rowptr, col, dinv, b2, Wo, bo, out);
}